// Round 2
// baseline (122.148 us; speedup 1.0000x reference)
//
#include <hip/hip_runtime.h>

// Problem constants
#define B_ 4
#define T_ 1024
#define D_ 1024
#define H_ 2048
#define E_ 8
#define N_ (B_ * T_)

// --------------------------------------------------------------------------
// Kernel A: w2sum[r] = sum_d w2_flat[r, d], r in [0, E*H), row = D contiguous.
// 1024 blocks x 256 thr = 4096 waves; each wave reduces 4 consecutive rows.
// 16 independent float4 loads in flight per wave; reduce tail amortized 4x.
// --------------------------------------------------------------------------
__global__ __launch_bounds__(256) void w2sum_kernel(const float* __restrict__ w2,
                                                    float* __restrict__ w2sum) {
    int wave = (blockIdx.x * 256 + threadIdx.x) >> 6;   // 0..4095
    int lane = threadIdx.x & 63;
    const float4* p = (const float4*)(w2 + (size_t)wave * 4 * D_) + lane;

    float4 a00 = p[0],        a01 = p[64],       a02 = p[128],      a03 = p[192];
    float4 a10 = p[256 + 0],  a11 = p[256 + 64], a12 = p[256 + 128], a13 = p[256 + 192];
    float4 a20 = p[512 + 0],  a21 = p[512 + 64], a22 = p[512 + 128], a23 = p[512 + 192];
    float4 a30 = p[768 + 0],  a31 = p[768 + 64], a32 = p[768 + 128], a33 = p[768 + 192];

    float acc0 = (a00.x+a00.y+a00.z+a00.w)+(a01.x+a01.y+a01.z+a01.w)
               + (a02.x+a02.y+a02.z+a02.w)+(a03.x+a03.y+a03.z+a03.w);
    float acc1 = (a10.x+a10.y+a10.z+a10.w)+(a11.x+a11.y+a11.z+a11.w)
               + (a12.x+a12.y+a12.z+a12.w)+(a13.x+a13.y+a13.z+a13.w);
    float acc2 = (a20.x+a20.y+a20.z+a20.w)+(a21.x+a21.y+a21.z+a21.w)
               + (a22.x+a22.y+a22.z+a22.w)+(a23.x+a23.y+a23.z+a23.w);
    float acc3 = (a30.x+a30.y+a30.z+a30.w)+(a31.x+a31.y+a31.z+a31.w)
               + (a32.x+a32.y+a32.z+a32.w)+(a33.x+a33.y+a33.z+a33.w);

#pragma unroll
    for (int off = 32; off >= 1; off >>= 1) {
        acc0 += __shfl_xor(acc0, off, 64);
        acc1 += __shfl_xor(acc1, off, 64);
        acc2 += __shfl_xor(acc2, off, 64);
        acc3 += __shfl_xor(acc3, off, 64);
    }
    if (lane == 0) {
        float* o = w2sum + wave * 4;
        o[0] = acc0; o[1] = acc1; o[2] = acc2; o[3] = acc3;
    }
}

// --------------------------------------------------------------------------
// Kernel B: v[r] = dot(w1_flat[r, :], w2sum[e(r), :]), r in [0, E*D), row = H.
// 1024 blocks x 256 thr = 4096 waves; each wave does 2 consecutive rows
// (same expert -> shared w2sum fragment load). c[e] folded into waves 0..7.
// --------------------------------------------------------------------------
__global__ __launch_bounds__(256) void v_build_kernel(const float* __restrict__ w1,
                                                      const float* __restrict__ w2sum,
                                                      const float* __restrict__ b1,
                                                      const float* __restrict__ b2,
                                                      float* __restrict__ v,
                                                      float* __restrict__ c) {
    int gw = (blockIdx.x * 256 + threadIdx.x) >> 6;     // 0..4095
    int lane = threadIdx.x & 63;
    int row0 = gw * 2;
    int e = row0 >> 10;                                  // row / D_
    const float4* a  = (const float4*)(w1 + (size_t)row0 * H_) + lane;
    const float4* b  = a + (H_ / 4);                     // next row, +H_ floats
    const float4* ws = (const float4*)(w2sum + e * H_) + lane;

    float acc0 = 0.f, acc1 = 0.f;
#pragma unroll
    for (int k = 0; k < H_ / 256; ++k) {                // 8 iters
        float4 wv = ws[k * 64];
        float4 a0 = a[k * 64];
        float4 a1 = b[k * 64];
        acc0 += a0.x * wv.x + a0.y * wv.y + a0.z * wv.z + a0.w * wv.w;
        acc1 += a1.x * wv.x + a1.y * wv.y + a1.z * wv.z + a1.w * wv.w;
    }
#pragma unroll
    for (int off = 32; off >= 1; off >>= 1) {
        acc0 += __shfl_xor(acc0, off, 64);
        acc1 += __shfl_xor(acc1, off, 64);
    }
    if (lane == 0) { v[row0] = acc0; v[row0 + 1] = acc1; }

    // c[e] = dot(b1[e,:], w2sum[e,:]) + sum_d b2[e,d]  -- waves 0..7, one per expert
    if (gw < E_) {
        float s = 0.f;
        for (int k = lane; k < H_; k += 64) s += b1[gw * H_ + k] * w2sum[gw * H_ + k];
        for (int k = lane; k < D_; k += 64) s += b2[gw * D_ + k];
#pragma unroll
        for (int off = 32; off >= 1; off >>= 1) s += __shfl_xor(s, off, 64);
        if (lane == 0) c[gw] = s;
    }
}

// --------------------------------------------------------------------------
// Kernel C: per-token gating + collapsed expert sum, then fused log-softmax
// done by the last block to finish (device-scope completion counter).
//   logits[e] = x[n,:].wg[:,e] ; dv[e] = x[n,:].v[e,:]
//   top-2 (tie -> lower index); g1 = 1/(1+exp(l0-l1)); s[n] = sum g*(dv+c)
// 1024 blocks x 256 thr, one wave per token.
// --------------------------------------------------------------------------
__global__ __launch_bounds__(256) void token_lsm_kernel(const float* __restrict__ x,
                                                        const float* __restrict__ wg,
                                                        const float* __restrict__ v,
                                                        const float* __restrict__ c,
                                                        float* __restrict__ s,
                                                        float* __restrict__ out,
                                                        unsigned* __restrict__ counter) {
    int n = (blockIdx.x * 256 + threadIdx.x) >> 6;      // token id
    int lane = threadIdx.x & 63;
    const float* xr = x + (size_t)n * D_;

    float lg[E_] = {0.f,0.f,0.f,0.f,0.f,0.f,0.f,0.f};
    float dv[E_] = {0.f,0.f,0.f,0.f,0.f,0.f,0.f,0.f};

#pragma unroll
    for (int k = 0; k < D_ / 64; ++k) {                 // 16 iters
        int d = lane + 64 * k;
        float xv = xr[d];
        const float4* wgp = (const float4*)(wg + (size_t)d * E_);
        float4 g0 = wgp[0], g1 = wgp[1];
        lg[0] += xv * g0.x; lg[1] += xv * g0.y;
        lg[2] += xv * g0.z; lg[3] += xv * g0.w;
        lg[4] += xv * g1.x; lg[5] += xv * g1.y;
        lg[6] += xv * g1.z; lg[7] += xv * g1.w;
#pragma unroll
        for (int e = 0; e < E_; ++e) dv[e] += xv * v[e * D_ + d];
    }

#pragma unroll
    for (int off = 32; off >= 1; off >>= 1) {
#pragma unroll
        for (int e = 0; e < E_; ++e) {
            lg[e] += __shfl_xor(lg[e], off, 64);
            dv[e] += __shfl_xor(dv[e], off, 64);
        }
    }

    if (lane == 0) {
        int e0 = 0;
#pragma unroll
        for (int e = 1; e < E_; ++e) if (lg[e] > lg[e0]) e0 = e;
        int e1 = (e0 == 0) ? 1 : 0;
#pragma unroll
        for (int e = 0; e < E_; ++e) {
            if (e == e0) continue;
            if (lg[e] > lg[e1]) e1 = e;
        }
        float l0 = lg[e0], l1 = lg[e1];
        float g1w = 1.f / (1.f + expf(l0 - l1));
        float g0w = 1.f - g1w;
        s[n] = g0w * (dv[e0] + c[e0]) + g1w * (dv[e1] + c[e1]);
    }

    // ---- completion-counter handoff: last block computes the log-softmax ----
    __threadfence();                                    // release s writes (device scope)
    __syncthreads();
    __shared__ int is_last;
    if (threadIdx.x == 0)
        is_last = (atomicAdd(counter, 1u) == (unsigned)(gridDim.x - 1)) ? 1 : 0;
    __syncthreads();
    if (!is_last) return;
    __threadfence();                                    // acquire: see all s writes

    // wave w handles batch row w (T_=1024 values, 16 per lane)
    int brow = threadIdx.x >> 6;                        // 0..3
    const float* row = s + (size_t)brow * T_;
    float vals[16];
    float mx = -3.0e38f;
#pragma unroll
    for (int k = 0; k < 16; ++k) {
        vals[k] = row[lane + 64 * k];
        mx = fmaxf(mx, vals[k]);
    }
#pragma unroll
    for (int off = 32; off >= 1; off >>= 1) mx = fmaxf(mx, __shfl_xor(mx, off, 64));
    float sm = 0.f;
#pragma unroll
    for (int k = 0; k < 16; ++k) sm += expf(vals[k] - mx);
#pragma unroll
    for (int off = 32; off >= 1; off >>= 1) sm += __shfl_xor(sm, off, 64);
    float lse = mx + logf(sm);
#pragma unroll
    for (int k = 0; k < 16; ++k) out[(size_t)brow * T_ + lane + 64 * k] = vals[k] - lse;
}

// --------------------------------------------------------------------------
extern "C" void kernel_launch(void* const* d_in, const int* in_sizes, int n_in,
                              void* d_out, int out_size, void* d_ws, size_t ws_size,
                              hipStream_t stream) {
    const float* x  = (const float*)d_in[0];   // [B, T, D]
    const float* wg = (const float*)d_in[1];   // [D, E]
    const float* w1 = (const float*)d_in[2];   // [E, D, H]
    const float* b1 = (const float*)d_in[3];   // [E, H]
    const float* w2 = (const float*)d_in[4];   // [E, H, D]
    const float* b2 = (const float*)d_in[5];   // [E, D]
    float* out = (float*)d_out;                // [B, T]

    float* ws      = (float*)d_ws;
    float* w2sum   = ws;                 // E*H = 16384 floats
    float* v       = ws + 16384;         // E*D =  8192 floats
    float* c       = ws + 24576;         // E   =     8 floats
    float* s       = ws + 24592;         // N   =  4096 floats
    unsigned* counter = (unsigned*)(ws + 28688);

    // counter = 0 each launch (memset node is graph-capturable; deterministic)
    hipMemsetAsync(counter, 0, sizeof(unsigned), stream);

    // A: 16384 rows, 4/wave -> 4096 waves -> 1024 blocks
    w2sum_kernel<<<dim3(1024), dim3(256), 0, stream>>>(w2, w2sum);
    // B: 8192 rows, 2/wave -> 4096 waves -> 1024 blocks (+ c[e] in waves 0..7)
    v_build_kernel<<<dim3(1024), dim3(256), 0, stream>>>(w1, w2sum, b1, b2, v, c);
    // C: 4096 tokens, 1/wave -> 1024 blocks; last block does the log-softmax
    token_lsm_kernel<<<dim3(1024), dim3(256), 0, stream>>>(x, wg, v, c, s, out, counter);
}

// Round 3
// 64.235 us; speedup vs baseline: 1.9016x; 1.9016x over previous
//
#include <hip/hip_runtime.h>

// Problem constants
#define B_ 4
#define T_ 1024
#define D_ 1024
#define H_ 2048
#define E_ 8
#define N_ (B_ * T_)

// --------------------------------------------------------------------------
// Kernel A: w2sum[r] = sum_d w2_flat[r, d], r in [0, E*H), row = D contiguous.
// 1024 blocks x 256 thr = 4096 waves; each wave reduces 4 consecutive rows.
// --------------------------------------------------------------------------
__global__ __launch_bounds__(256) void w2sum_kernel(const float* __restrict__ w2,
                                                    float* __restrict__ w2sum) {
    int wave = (blockIdx.x * 256 + threadIdx.x) >> 6;   // 0..4095
    int lane = threadIdx.x & 63;
    const float4* p = (const float4*)(w2 + (size_t)wave * 4 * D_) + lane;

    float4 a00 = p[0],        a01 = p[64],       a02 = p[128],       a03 = p[192];
    float4 a10 = p[256 + 0],  a11 = p[256 + 64], a12 = p[256 + 128], a13 = p[256 + 192];
    float4 a20 = p[512 + 0],  a21 = p[512 + 64], a22 = p[512 + 128], a23 = p[512 + 192];
    float4 a30 = p[768 + 0],  a31 = p[768 + 64], a32 = p[768 + 128], a33 = p[768 + 192];

    float acc0 = (a00.x+a00.y+a00.z+a00.w)+(a01.x+a01.y+a01.z+a01.w)
               + (a02.x+a02.y+a02.z+a02.w)+(a03.x+a03.y+a03.z+a03.w);
    float acc1 = (a10.x+a10.y+a10.z+a10.w)+(a11.x+a11.y+a11.z+a11.w)
               + (a12.x+a12.y+a12.z+a12.w)+(a13.x+a13.y+a13.z+a13.w);
    float acc2 = (a20.x+a20.y+a20.z+a20.w)+(a21.x+a21.y+a21.z+a21.w)
               + (a22.x+a22.y+a22.z+a22.w)+(a23.x+a23.y+a23.z+a23.w);
    float acc3 = (a30.x+a30.y+a30.z+a30.w)+(a31.x+a31.y+a31.z+a31.w)
               + (a32.x+a32.y+a32.z+a32.w)+(a33.x+a33.y+a33.z+a33.w);

#pragma unroll
    for (int off = 32; off >= 1; off >>= 1) {
        acc0 += __shfl_xor(acc0, off, 64);
        acc1 += __shfl_xor(acc1, off, 64);
        acc2 += __shfl_xor(acc2, off, 64);
        acc3 += __shfl_xor(acc3, off, 64);
    }
    if (lane == 0) {
        float* o = w2sum + wave * 4;
        o[0] = acc0; o[1] = acc1; o[2] = acc2; o[3] = acc3;
    }
}

// --------------------------------------------------------------------------
// Kernel B: for row r = e*D + d:  vT[d*E + e] = dot(w1[e,d,:], w2sum[e,:]).
// Transposed write so the token kernel can float4-load 8 experts at once.
// 1024 blocks x 256 thr = 4096 waves; each wave does 2 consecutive rows
// (same expert -> shared w2sum fragment). c[e] folded into waves 0..7.
// --------------------------------------------------------------------------
__global__ __launch_bounds__(256) void v_build_kernel(const float* __restrict__ w1,
                                                      const float* __restrict__ w2sum,
                                                      const float* __restrict__ b1,
                                                      const float* __restrict__ b2,
                                                      float* __restrict__ vT,
                                                      float* __restrict__ c) {
    int gw = (blockIdx.x * 256 + threadIdx.x) >> 6;     // 0..4095
    int lane = threadIdx.x & 63;
    int row0 = gw * 2;
    int e  = row0 >> 10;                                 // row / D_
    int d0 = row0 & (D_ - 1);                            // row % D_
    const float4* a  = (const float4*)(w1 + (size_t)row0 * H_) + lane;
    const float4* b  = a + (H_ / 4);                     // next row
    const float4* ws = (const float4*)(w2sum + e * H_) + lane;

    float acc0 = 0.f, acc1 = 0.f;
#pragma unroll
    for (int k = 0; k < H_ / 256; ++k) {                // 8 iters
        float4 wv = ws[k * 64];
        float4 a0 = a[k * 64];
        float4 a1 = b[k * 64];
        acc0 += a0.x * wv.x + a0.y * wv.y + a0.z * wv.z + a0.w * wv.w;
        acc1 += a1.x * wv.x + a1.y * wv.y + a1.z * wv.z + a1.w * wv.w;
    }
#pragma unroll
    for (int off = 32; off >= 1; off >>= 1) {
        acc0 += __shfl_xor(acc0, off, 64);
        acc1 += __shfl_xor(acc1, off, 64);
    }
    if (lane == 0) {
        vT[(size_t)d0 * E_ + e]       = acc0;
        vT[(size_t)(d0 + 1) * E_ + e] = acc1;
    }

    // c[e] = dot(b1[e,:], w2sum[e,:]) + sum_d b2[e,d]  -- waves 0..7
    if (gw < E_) {
        float s = 0.f;
        for (int k = lane; k < H_; k += 64) s += b1[gw * H_ + k] * w2sum[gw * H_ + k];
        for (int k = lane; k < D_; k += 64) s += b2[gw * D_ + k];
#pragma unroll
        for (int off = 32; off >= 1; off >>= 1) s += __shfl_xor(s, off, 64);
        if (lane == 0) c[gw] = s;
    }
}

// --------------------------------------------------------------------------
// Kernel C: per-token gating + collapsed expert sum. 2 tokens per wave.
//   logits[e] = x[n,:].wg[:,e] ; dv[e] = x[n,:].vT[:,e]
//   top-2 (tie -> lower index); g1 = 1/(1+exp(l0-l1)); s[n] = sum g*(dv+c)
// 512 blocks x 256 thr = 2048 waves.
// --------------------------------------------------------------------------
__global__ __launch_bounds__(256) void token_kernel(const float* __restrict__ x,
                                                    const float* __restrict__ wg,
                                                    const float* __restrict__ vT,
                                                    const float* __restrict__ c,
                                                    float* __restrict__ s) {
    int w = (blockIdx.x * 256 + threadIdx.x) >> 6;      // 0..2047
    int lane = threadIdx.x & 63;
    int n0 = w * 2;
    const float* x0 = x + (size_t)n0 * D_;
    const float* x1 = x0 + D_;

    float lgA[E_] = {0.f,0.f,0.f,0.f,0.f,0.f,0.f,0.f};
    float dvA[E_] = {0.f,0.f,0.f,0.f,0.f,0.f,0.f,0.f};
    float lgB[E_] = {0.f,0.f,0.f,0.f,0.f,0.f,0.f,0.f};
    float dvB[E_] = {0.f,0.f,0.f,0.f,0.f,0.f,0.f,0.f};

#pragma unroll
    for (int k = 0; k < D_ / 64; ++k) {                 // 16 iters
        int d = lane + 64 * k;
        float xa = x0[d];
        float xb = x1[d];
        const float4* wgp = (const float4*)(wg + (size_t)d * E_);
        const float4* vp  = (const float4*)(vT + (size_t)d * E_);
        float4 g0 = wgp[0], g1 = wgp[1];
        float4 v0 = vp[0],  v1 = vp[1];
        lgA[0] += xa * g0.x; lgA[1] += xa * g0.y; lgA[2] += xa * g0.z; lgA[3] += xa * g0.w;
        lgA[4] += xa * g1.x; lgA[5] += xa * g1.y; lgA[6] += xa * g1.z; lgA[7] += xa * g1.w;
        dvA[0] += xa * v0.x; dvA[1] += xa * v0.y; dvA[2] += xa * v0.z; dvA[3] += xa * v0.w;
        dvA[4] += xa * v1.x; dvA[5] += xa * v1.y; dvA[6] += xa * v1.z; dvA[7] += xa * v1.w;
        lgB[0] += xb * g0.x; lgB[1] += xb * g0.y; lgB[2] += xb * g0.z; lgB[3] += xb * g0.w;
        lgB[4] += xb * g1.x; lgB[5] += xb * g1.y; lgB[6] += xb * g1.z; lgB[7] += xb * g1.w;
        dvB[0] += xb * v0.x; dvB[1] += xb * v0.y; dvB[2] += xb * v0.z; dvB[3] += xb * v0.w;
        dvB[4] += xb * v1.x; dvB[5] += xb * v1.y; dvB[6] += xb * v1.z; dvB[7] += xb * v1.w;
    }

#pragma unroll
    for (int off = 32; off >= 1; off >>= 1) {
#pragma unroll
        for (int e = 0; e < E_; ++e) {
            lgA[e] += __shfl_xor(lgA[e], off, 64);
            dvA[e] += __shfl_xor(dvA[e], off, 64);
            lgB[e] += __shfl_xor(lgB[e], off, 64);
            dvB[e] += __shfl_xor(dvB[e], off, 64);
        }
    }

    if (lane == 0 || lane == 32) {
        const float* lg = (lane == 0) ? lgA : lgB;
        const float* dv = (lane == 0) ? dvA : dvB;
        int n = (lane == 0) ? n0 : (n0 + 1);
        int e0 = 0;
#pragma unroll
        for (int e = 1; e < E_; ++e) if (lg[e] > lg[e0]) e0 = e;
        int e1 = (e0 == 0) ? 1 : 0;
#pragma unroll
        for (int e = 0; e < E_; ++e) {
            if (e == e0) continue;
            if (lg[e] > lg[e1]) e1 = e;
        }
        float l0 = lg[e0], l1 = lg[e1];
        float g1w = 1.f / (1.f + expf(l0 - l1));
        float g0w = 1.f - g1w;
        s[n] = g0w * (dv[e0] + c[e0]) + g1w * (dv[e1] + c[e1]);
    }
}

// --------------------------------------------------------------------------
// Kernel D: out[b, t] = s[b, t] - logsumexp_t(s[b, :]).
// One block, 4 waves, wave per batch row; 16 values per lane.
// --------------------------------------------------------------------------
__global__ __launch_bounds__(256) void lsm_kernel(const float* __restrict__ s,
                                                  float* __restrict__ out) {
    int brow = threadIdx.x >> 6;                        // 0..3
    int lane = threadIdx.x & 63;
    const float* row = s + (size_t)brow * T_;
    float vals[16];
    float mx = -3.0e38f;
#pragma unroll
    for (int k = 0; k < 16; ++k) {
        vals[k] = row[lane + 64 * k];
        mx = fmaxf(mx, vals[k]);
    }
#pragma unroll
    for (int off = 32; off >= 1; off >>= 1) mx = fmaxf(mx, __shfl_xor(mx, off, 64));
    float sm = 0.f;
#pragma unroll
    for (int k = 0; k < 16; ++k) sm += expf(vals[k] - mx);
#pragma unroll
    for (int off = 32; off >= 1; off >>= 1) sm += __shfl_xor(sm, off, 64);
    float lse = mx + logf(sm);
#pragma unroll
    for (int k = 0; k < 16; ++k) out[(size_t)brow * T_ + lane + 64 * k] = vals[k] - lse;
}

// --------------------------------------------------------------------------
extern "C" void kernel_launch(void* const* d_in, const int* in_sizes, int n_in,
                              void* d_out, int out_size, void* d_ws, size_t ws_size,
                              hipStream_t stream) {
    const float* x  = (const float*)d_in[0];   // [B, T, D]
    const float* wg = (const float*)d_in[1];   // [D, E]
    const float* w1 = (const float*)d_in[2];   // [E, D, H]
    const float* b1 = (const float*)d_in[3];   // [E, H]
    const float* w2 = (const float*)d_in[4];   // [E, H, D]
    const float* b2 = (const float*)d_in[5];   // [E, D]
    float* out = (float*)d_out;                // [B, T]

    float* ws     = (float*)d_ws;
    float* w2sum  = ws;                 // E*H = 16384 floats
    float* vT     = ws + 16384;         // D*E =  8192 floats (transposed: [D][E])
    float* c      = ws + 24576;         // E   =     8 floats
    float* s      = ws + 24592;         // N   =  4096 floats

    // A: 16384 rows, 4/wave -> 4096 waves -> 1024 blocks
    w2sum_kernel<<<dim3(1024), dim3(256), 0, stream>>>(w2, w2sum);
    // B: 8192 rows, 2/wave -> 4096 waves -> 1024 blocks (+ c[e] in waves 0..7)
    v_build_kernel<<<dim3(1024), dim3(256), 0, stream>>>(w1, w2sum, b1, b2, vT, c);
    // C: 4096 tokens, 2/wave -> 2048 waves -> 512 blocks
    token_kernel<<<dim3(512), dim3(256), 0, stream>>>(x, wg, vT, c, s);
    // D: log-softmax over T per batch row, single block
    lsm_kernel<<<dim3(1), dim3(256), 0, stream>>>(s, out);
}

// Round 4
// 63.641 us; speedup vs baseline: 1.9193x; 1.0093x over previous
//
#include <hip/hip_runtime.h>

// Problem constants
#define B_ 4
#define T_ 1024
#define D_ 1024
#define H_ 2048
#define E_ 8
#define N_ (B_ * T_)

// --------------------------------------------------------------------------
// Kernel A: w2sum[r] = sum_d w2_flat[r, d], r in [0, E*H), row = D contiguous.
// 1024 blocks x 256 thr = 4096 waves; each wave reduces 4 consecutive rows.
// 16 explicit float4 loads in flight per wave.
// --------------------------------------------------------------------------
__global__ __launch_bounds__(256) void w2sum_kernel(const float* __restrict__ w2,
                                                    float* __restrict__ w2sum) {
    int wave = (blockIdx.x * 256 + threadIdx.x) >> 6;   // 0..4095
    int lane = threadIdx.x & 63;
    const float4* p = (const float4*)(w2 + (size_t)wave * 4 * D_) + lane;

    float4 a00 = p[0],        a01 = p[64],       a02 = p[128],       a03 = p[192];
    float4 a10 = p[256 + 0],  a11 = p[256 + 64], a12 = p[256 + 128], a13 = p[256 + 192];
    float4 a20 = p[512 + 0],  a21 = p[512 + 64], a22 = p[512 + 128], a23 = p[512 + 192];
    float4 a30 = p[768 + 0],  a31 = p[768 + 64], a32 = p[768 + 128], a33 = p[768 + 192];

    float acc0 = (a00.x+a00.y+a00.z+a00.w)+(a01.x+a01.y+a01.z+a01.w)
               + (a02.x+a02.y+a02.z+a02.w)+(a03.x+a03.y+a03.z+a03.w);
    float acc1 = (a10.x+a10.y+a10.z+a10.w)+(a11.x+a11.y+a11.z+a11.w)
               + (a12.x+a12.y+a12.z+a12.w)+(a13.x+a13.y+a13.z+a13.w);
    float acc2 = (a20.x+a20.y+a20.z+a20.w)+(a21.x+a21.y+a21.z+a21.w)
               + (a22.x+a22.y+a22.z+a22.w)+(a23.x+a23.y+a23.z+a23.w);
    float acc3 = (a30.x+a30.y+a30.z+a30.w)+(a31.x+a31.y+a31.z+a31.w)
               + (a32.x+a32.y+a32.z+a32.w)+(a33.x+a33.y+a33.z+a33.w);

#pragma unroll
    for (int off = 32; off >= 1; off >>= 1) {
        acc0 += __shfl_xor(acc0, off, 64);
        acc1 += __shfl_xor(acc1, off, 64);
        acc2 += __shfl_xor(acc2, off, 64);
        acc3 += __shfl_xor(acc3, off, 64);
    }
    if (lane == 0) {
        float* o = w2sum + wave * 4;
        o[0] = acc0; o[1] = acc1; o[2] = acc2; o[3] = acc3;
    }
}

// --------------------------------------------------------------------------
// Kernel B: for row r = e*D + d:  vT[d*E + e] = dot(w1[e,d,:], w2sum[e,:]).
// w2sum[e] fragment hoisted into 8 float4 REGISTERS (loop-invariant across
// rows); 16 explicit independent float4 row loads in flight per wave.
// 1024 blocks x 256 thr = 4096 waves; 2 consecutive rows per wave (same
// expert since D is a multiple of 2). c[e] folded into waves 0..7.
// --------------------------------------------------------------------------
__global__ __launch_bounds__(256) void v_build_kernel(const float* __restrict__ w1,
                                                      const float* __restrict__ w2sum,
                                                      const float* __restrict__ b1,
                                                      const float* __restrict__ b2,
                                                      float* __restrict__ vT,
                                                      float* __restrict__ c) {
    int gw = (blockIdx.x * 256 + threadIdx.x) >> 6;     // 0..4095
    int lane = threadIdx.x & 63;
    int row0 = gw * 2;
    int e  = row0 >> 10;                                 // row / D_
    int d0 = row0 & (D_ - 1);                            // row % D_

    const float4* ws = (const float4*)(w2sum + (size_t)e * H_) + lane;
    float4 s0 = ws[0],   s1 = ws[64],  s2 = ws[128], s3 = ws[192],
           s4 = ws[256], s5 = ws[320], s6 = ws[384], s7 = ws[448];

    const float4* a = (const float4*)(w1 + (size_t)row0 * H_) + lane;
    float4 a0 = a[0],   a1 = a[64],  a2 = a[128], a3 = a[192],
           a4 = a[256], a5 = a[320], a6 = a[384], a7 = a[448];
    const float4* b = a + (H_ / 4);                      // next row
    float4 b0 = b[0],   b1v = b[64], b2v = b[128], b3 = b[192],
           b4 = b[256], b5 = b[320], b6 = b[384],  b7 = b[448];

    float acc0 = a0.x*s0.x + a0.y*s0.y + a0.z*s0.z + a0.w*s0.w
               + a1.x*s1.x + a1.y*s1.y + a1.z*s1.z + a1.w*s1.w
               + a2.x*s2.x + a2.y*s2.y + a2.z*s2.z + a2.w*s2.w
               + a3.x*s3.x + a3.y*s3.y + a3.z*s3.z + a3.w*s3.w
               + a4.x*s4.x + a4.y*s4.y + a4.z*s4.z + a4.w*s4.w
               + a5.x*s5.x + a5.y*s5.y + a5.z*s5.z + a5.w*s5.w
               + a6.x*s6.x + a6.y*s6.y + a6.z*s6.z + a6.w*s6.w
               + a7.x*s7.x + a7.y*s7.y + a7.z*s7.z + a7.w*s7.w;
    float acc1 = b0.x*s0.x + b0.y*s0.y + b0.z*s0.z + b0.w*s0.w
               + b1v.x*s1.x + b1v.y*s1.y + b1v.z*s1.z + b1v.w*s1.w
               + b2v.x*s2.x + b2v.y*s2.y + b2v.z*s2.z + b2v.w*s2.w
               + b3.x*s3.x + b3.y*s3.y + b3.z*s3.z + b3.w*s3.w
               + b4.x*s4.x + b4.y*s4.y + b4.z*s4.z + b4.w*s4.w
               + b5.x*s5.x + b5.y*s5.y + b5.z*s5.z + b5.w*s5.w
               + b6.x*s6.x + b6.y*s6.y + b6.z*s6.z + b6.w*s6.w
               + b7.x*s7.x + b7.y*s7.y + b7.z*s7.z + b7.w*s7.w;

#pragma unroll
    for (int off = 32; off >= 1; off >>= 1) {
        acc0 += __shfl_xor(acc0, off, 64);
        acc1 += __shfl_xor(acc1, off, 64);
    }
    if (lane == 0) {
        vT[(size_t)d0 * E_ + e]       = acc0;
        vT[(size_t)(d0 + 1) * E_ + e] = acc1;
    }

    // c[e] = dot(b1[e,:], w2sum[e,:]) + sum_d b2[e,d]  -- waves 0..7
    if (gw < E_) {
        float s = 0.f;
        for (int k = lane; k < H_; k += 64) s += b1[gw * H_ + k] * w2sum[gw * H_ + k];
        for (int k = lane; k < D_; k += 64) s += b2[gw * D_ + k];
#pragma unroll
        for (int off = 32; off >= 1; off >>= 1) s += __shfl_xor(s, off, 64);
        if (lane == 0) c[gw] = s;
    }
}

// --------------------------------------------------------------------------
// Kernel C: per-token gating + collapsed expert sum. 2 tokens per wave.
//   logits[e] = x[n,:].wg[:,e] ; dv[e] = x[n,:].vT[:,e]
//   top-2 (tie -> lower index); g1 = 1/(1+exp(l0-l1)); s[n] = sum g*(dv+c)
// 512 blocks x 256 thr = 2048 waves.
// --------------------------------------------------------------------------
__global__ __launch_bounds__(256) void token_kernel(const float* __restrict__ x,
                                                    const float* __restrict__ wg,
                                                    const float* __restrict__ vT,
                                                    const float* __restrict__ c,
                                                    float* __restrict__ s) {
    int w = (blockIdx.x * 256 + threadIdx.x) >> 6;      // 0..2047
    int lane = threadIdx.x & 63;
    int n0 = w * 2;
    const float* x0 = x + (size_t)n0 * D_;
    const float* x1 = x0 + D_;

    float lgA[E_] = {0.f,0.f,0.f,0.f,0.f,0.f,0.f,0.f};
    float dvA[E_] = {0.f,0.f,0.f,0.f,0.f,0.f,0.f,0.f};
    float lgB[E_] = {0.f,0.f,0.f,0.f,0.f,0.f,0.f,0.f};
    float dvB[E_] = {0.f,0.f,0.f,0.f,0.f,0.f,0.f,0.f};

#pragma unroll
    for (int k = 0; k < D_ / 64; ++k) {                 // 16 iters
        int d = lane + 64 * k;
        float xa = x0[d];
        float xb = x1[d];
        const float4* wgp = (const float4*)(wg + (size_t)d * E_);
        const float4* vp  = (const float4*)(vT + (size_t)d * E_);
        float4 g0 = wgp[0], g1 = wgp[1];
        float4 v0 = vp[0],  v1 = vp[1];
        lgA[0] += xa * g0.x; lgA[1] += xa * g0.y; lgA[2] += xa * g0.z; lgA[3] += xa * g0.w;
        lgA[4] += xa * g1.x; lgA[5] += xa * g1.y; lgA[6] += xa * g1.z; lgA[7] += xa * g1.w;
        dvA[0] += xa * v0.x; dvA[1] += xa * v0.y; dvA[2] += xa * v0.z; dvA[3] += xa * v0.w;
        dvA[4] += xa * v1.x; dvA[5] += xa * v1.y; dvA[6] += xa * v1.z; dvA[7] += xa * v1.w;
        lgB[0] += xb * g0.x; lgB[1] += xb * g0.y; lgB[2] += xb * g0.z; lgB[3] += xb * g0.w;
        lgB[4] += xb * g1.x; lgB[5] += xb * g1.y; lgB[6] += xb * g1.z; lgB[7] += xb * g1.w;
        dvB[0] += xb * v0.x; dvB[1] += xb * v0.y; dvB[2] += xb * v0.z; dvB[3] += xb * v0.w;
        dvB[4] += xb * v1.x; dvB[5] += xb * v1.y; dvB[6] += xb * v1.z; dvB[7] += xb * v1.w;
    }

#pragma unroll
    for (int off = 32; off >= 1; off >>= 1) {
#pragma unroll
        for (int e = 0; e < E_; ++e) {
            lgA[e] += __shfl_xor(lgA[e], off, 64);
            dvA[e] += __shfl_xor(dvA[e], off, 64);
            lgB[e] += __shfl_xor(lgB[e], off, 64);
            dvB[e] += __shfl_xor(dvB[e], off, 64);
        }
    }

    if (lane == 0 || lane == 32) {
        const float* lg = (lane == 0) ? lgA : lgB;
        const float* dv = (lane == 0) ? dvA : dvB;
        int n = (lane == 0) ? n0 : (n0 + 1);
        int e0 = 0;
#pragma unroll
        for (int e = 1; e < E_; ++e) if (lg[e] > lg[e0]) e0 = e;
        int e1 = (e0 == 0) ? 1 : 0;
#pragma unroll
        for (int e = 0; e < E_; ++e) {
            if (e == e0) continue;
            if (lg[e] > lg[e1]) e1 = e;
        }
        float l0 = lg[e0], l1 = lg[e1];
        float g1w = 1.f / (1.f + expf(l0 - l1));
        float g0w = 1.f - g1w;
        s[n] = g0w * (dv[e0] + c[e0]) + g1w * (dv[e1] + c[e1]);
    }
}

// --------------------------------------------------------------------------
// Kernel D: out[b, t] = s[b, t] - logsumexp_t(s[b, :]).
// One block, 4 waves, wave per batch row; 16 values per lane.
// --------------------------------------------------------------------------
__global__ __launch_bounds__(256) void lsm_kernel(const float* __restrict__ s,
                                                  float* __restrict__ out) {
    int brow = threadIdx.x >> 6;                        // 0..3
    int lane = threadIdx.x & 63;
    const float* row = s + (size_t)brow * T_;
    float vals[16];
    float mx = -3.0e38f;
#pragma unroll
    for (int k = 0; k < 16; ++k) {
        vals[k] = row[lane + 64 * k];
        mx = fmaxf(mx, vals[k]);
    }
#pragma unroll
    for (int off = 32; off >= 1; off >>= 1) mx = fmaxf(mx, __shfl_xor(mx, off, 64));
    float sm = 0.f;
#pragma unroll
    for (int k = 0; k < 16; ++k) sm += expf(vals[k] - mx);
#pragma unroll
    for (int off = 32; off >= 1; off >>= 1) sm += __shfl_xor(sm, off, 64);
    float lse = mx + logf(sm);
#pragma unroll
    for (int k = 0; k < 16; ++k) out[(size_t)brow * T_ + lane + 64 * k] = vals[k] - lse;
}

// --------------------------------------------------------------------------
extern "C" void kernel_launch(void* const* d_in, const int* in_sizes, int n_in,
                              void* d_out, int out_size, void* d_ws, size_t ws_size,
                              hipStream_t stream) {
    const float* x  = (const float*)d_in[0];   // [B, T, D]
    const float* wg = (const float*)d_in[1];   // [D, E]
    const float* w1 = (const float*)d_in[2];   // [E, D, H]
    const float* b1 = (const float*)d_in[3];   // [E, H]
    const float* w2 = (const float*)d_in[4];   // [E, H, D]
    const float* b2 = (const float*)d_in[5];   // [E, D]
    float* out = (float*)d_out;                // [B, T]

    float* ws     = (float*)d_ws;
    float* w2sum  = ws;                 // E*H = 16384 floats
    float* vT     = ws + 16384;         // D*E =  8192 floats (transposed: [D][E])
    float* c      = ws + 24576;         // E   =     8 floats
    float* s      = ws + 24592;         // N   =  4096 floats

    // A: 16384 rows, 4/wave -> 4096 waves -> 1024 blocks
    w2sum_kernel<<<dim3(1024), dim3(256), 0, stream>>>(w2, w2sum);
    // B: 8192 rows, 2/wave -> 4096 waves -> 1024 blocks (+ c[e] in waves 0..7)
    v_build_kernel<<<dim3(1024), dim3(256), 0, stream>>>(w1, w2sum, b1, b2, vT, c);
    // C: 4096 tokens, 2/wave -> 2048 waves -> 512 blocks
    token_kernel<<<dim3(512), dim3(256), 0, stream>>>(x, wg, vT, c, s);
    // D: log-softmax over T per batch row, single block
    lsm_kernel<<<dim3(1), dim3(256), 0, stream>>>(s, out);
}